// Round 13
// baseline (3179.987 us; speedup 1.0000x reference)
//
#include <hip/hip_runtime.h>
#include <hip/hip_bf16.h>
#include <cstdint>

#define HIDDEN 1024
#define INPUT  256
#define BATCH  64
#define TSTEPS 512
#define NGCOL  4096      // 4*HIDDEN
#define KTOT   1280      // HIDDEN + INPUT
#define HBUFN  65536     // BATCH*HIDDEN u32 per parity buffer

typedef __attribute__((ext_vector_type(8))) short bf16x8;
typedef __attribute__((ext_vector_type(4))) float f32x4;
typedef unsigned long long u64;
typedef unsigned int u32;

__device__ inline short f2bs(float f) {
    union { __hip_bfloat16 h; short s; } u;
    u.h = __float2bfloat16(f);
    return u.s;
}
__device__ inline unsigned short f2bu(float f) {
    union { __hip_bfloat16 h; unsigned short s; } u;
    u.h = __float2bfloat16(f);
    return u.s;
}

// ---------------------------------------------------------------------------
// P1: build unified transposed bf16 weights Wt[4096 cols][1280 k]
__global__ __launch_bounds__(256) void build_wt(
    const float* __restrict__ Whh, const float* __restrict__ Wih,
    __hip_bfloat16* __restrict__ Wt)
{
    int t = blockIdx.x * 256 + threadIdx.x;   // 0 .. 4096*80-1
    int col = t & 4095;
    int k0  = (t >> 12) * 16;                 // 0..1264
    __hip_bfloat16 tmp[16];
    if (k0 < HIDDEN) {
        #pragma unroll
        for (int i = 0; i < 16; ++i)
            tmp[i] = __float2bfloat16(Whh[(size_t)(k0 + i) * NGCOL + col]);
    } else {
        #pragma unroll
        for (int i = 0; i < 16; ++i)
            tmp[i] = __float2bfloat16(Wih[(size_t)(k0 - HIDDEN + i) * NGCOL + col]);
    }
    #pragma unroll
    for (int i = 0; i < 16; ++i)
        Wt[(size_t)col * KTOT + k0 + i] = tmp[i];
}

// ---------------------------------------------------------------------------
// P2: bias = b_ih + b_hh ; zero both epoch-coded h buffers (epoch 0, h=0)
__global__ __launch_bounds__(256) void init_state(
    const float* __restrict__ bih, const float* __restrict__ bhh,
    float* __restrict__ bias, u32* __restrict__ hbuf)
{
    int i = blockIdx.x * 256 + threadIdx.x;   // 131072 threads
    if (i < NGCOL) bias[i] = bih[i] + bhh[i];
    hbuf[i] = 0u;                              // both parity buffers
}

// ---------------------------------------------------------------------------
// Persistent LSTM, G=8 x C=32 geometry (8 batch rows x 32 h-cols per wg).
// Per-CU coherent h ingest halved to 32 KB/step; clique fan-in 32.
// In-band epoch protocol (r6/r12, proven): u32 = (epoch<<16)|bf16, burst
// 16 parallel u64 + verify + parallel re-sweep. No flags, no drains.
// Mapping (placement heuristic only): i%8 = XCD slot -> cg in {4k..4k+3},
// so each XCD's W working set = 4 x 328KB = 1.3 MB (L2-resident).
// MFMA A rows 8..15 zero-padded (M=8 real).
__global__ __launch_bounds__(512, 2) void lstm_persist(
    const __hip_bfloat16* __restrict__ Wt,
    const float* __restrict__ x,
    u32* __restrict__ hbuf,              // [2][64][1024] epoch-coded
    float* __restrict__ hf,
    const float* __restrict__ bias)
{
    __shared__ float pbuf[8][8][132];    // [wave][row][tilecol 0..127]+pad

    const int tid  = threadIdx.x;
    const int i    = blockIdx.x;
    const int k8   = i & 7;              // XCD slot under %8 round-robin
    const int m    = i >> 3;
    const int bg   = m & 7;              // 0..7  (8 rows each)
    const int cg   = k8 * 4 + (m >> 3);  // 0..31 (32 h-cols each)
    const int wave = tid >> 6;
    const int lane = tid & 63;
    const int l15  = lane & 15;
    const int l4   = lane >> 4;
    const int b0   = bg * 8;
    const int n0   = cg * 32;

    // 8 B-column base pointers: tilecol = ct*16+l15 -> gate g, hcol hc
    const __hip_bfloat16* wcol[8];
    #pragma unroll
    for (int ct = 0; ct < 8; ++ct) {
        const int tilecol = ct * 16 + l15;
        const int g  = tilecol >> 5;
        const int hc = tilecol & 31;
        wcol[ct] = Wt + (size_t)(g * 1024 + n0 + hc) * KTOT;
    }

    // reducer state (tid<256): row = tid>>5 (0..7), hcol = tid&31
    const int rrow = tid >> 5;
    const int rhc  = tid & 31;
    float creg = 0.f;
    float bi = 0.f, bfr = 0.f, bgg = 0.f, bo = 0.f;
    if (tid < 256) {
        bi  = bias[0 * 1024 + n0 + rhc];
        bfr = bias[1 * 1024 + n0 + rhc];
        bgg = bias[2 * 1024 + n0 + rhc];
        bo  = bias[3 * 1024 + n0 + rhc];
    }

    const bool act = (l15 < 8);          // A rows 8..15 are zero-padded
    const int  hrow = b0 + l15;          // valid when act
    const float* xrow = x + ((size_t)hrow * TSTEPS) * INPUT + wave * 32 + l4 * 8;
    const int  kkx = 1024 + wave * 32 + l4 * 8;   // x K-range in Wt

    for (int t = 0; t < TSTEPS; ++t) {
        const u32* hb = hbuf + (t & 1) * HBUFN;        // holds epoch t
        u32*       ho = hbuf + ((t + 1) & 1) * HBUFN;  // receives epoch t+1

        // ---- x fragment + x-part MFMAs first (independent of h)
        bf16x8 afx = {0, 0, 0, 0, 0, 0, 0, 0};
        if (act) {
            const float* xf = xrow + (size_t)t * INPUT;
            float4 pa = *(const float4*)(xf);
            float4 pb = *(const float4*)(xf + 4);
            afx[0] = f2bs(pa.x); afx[1] = f2bs(pa.y); afx[2] = f2bs(pa.z); afx[3] = f2bs(pa.w);
            afx[4] = f2bs(pb.x); afx[5] = f2bs(pb.y); afx[6] = f2bs(pb.z); afx[7] = f2bs(pb.w);
        }
        f32x4 acc[8];
        #pragma unroll
        for (int ct = 0; ct < 8; ++ct) acc[ct] = (f32x4){0.f, 0.f, 0.f, 0.f};
        #pragma unroll
        for (int ct = 0; ct < 8; ++ct)
            acc[ct] = __builtin_amdgcn_mfma_f32_16x16x32_bf16(
                afx, *(const bf16x8*)(wcol[ct] + kkx), acc[ct], 0, 0, 0);

        // ---- burst-load h slice (16 parallel u64) + verify; parallel re-sweep
        const u64 want  = ((u64)(u32)t << 16) | ((u64)(u32)t << 48);
        const u64 emask = 0xFFFF0000FFFF0000ull;
        u64 hq[4][4];
        u64 bad = 0;
        if (act) {
            #pragma unroll
            for (int c5 = 0; c5 < 4; ++c5) {
                const u64* hp = (const u64*)(hb + hrow * HIDDEN + (wave + c5 * 8) * 32 + l4 * 8);
                #pragma unroll
                for (int q = 0; q < 4; ++q) {
                    hq[c5][q] = __hip_atomic_load(hp + q, __ATOMIC_RELAXED,
                                                  __HIP_MEMORY_SCOPE_AGENT);
                    bad |= (hq[c5][q] ^ want) & emask;
                }
            }
        }
        while (!__all(bad == 0)) {
            __builtin_amdgcn_s_sleep(1);
            bad = 0;
            if (act) {
                #pragma unroll
                for (int c5 = 0; c5 < 4; ++c5) {
                    const u64* hp = (const u64*)(hb + hrow * HIDDEN + (wave + c5 * 8) * 32 + l4 * 8);
                    #pragma unroll
                    for (int q = 0; q < 4; ++q) {
                        hq[c5][q] = __hip_atomic_load(hp + q, __ATOMIC_RELAXED,
                                                      __HIP_MEMORY_SCOPE_AGENT);
                        bad |= (hq[c5][q] ^ want) & emask;
                    }
                }
            }
        }

        // ---- h MFMAs: repack u32-coded -> bf16 pairs, stream B from L2
        #pragma unroll
        for (int c5 = 0; c5 < 4; ++c5) {
            bf16x8 af = {0, 0, 0, 0, 0, 0, 0, 0};
            if (act) {
                union { u32 p[4]; bf16x8 v; } u;
                #pragma unroll
                for (int q = 0; q < 4; ++q) {
                    const u64 d = hq[c5][q];
                    u.p[q] = (u32)(d & 0xFFFFu) | ((u32)(d >> 32) << 16);
                }
                af = u.v;
            }
            const int kk = (wave + c5 * 8) * 32 + l4 * 8;
            #pragma unroll
            for (int ct = 0; ct < 8; ++ct)
                acc[ct] = __builtin_amdgcn_mfma_f32_16x16x32_bf16(
                    af, *(const bf16x8*)(wcol[ct] + kk), acc[ct], 0, 0, 0);
        }

        // D layout: row = l4*4 + r (only rows 0..7 valid -> l4<2), col = l15
        if (l4 < 2) {
            #pragma unroll
            for (int r = 0; r < 4; ++r) {
                const int row = l4 * 4 + r;
                #pragma unroll
                for (int ct = 0; ct < 8; ++ct)
                    pbuf[wave][row][ct * 16 + l15] = acc[ct][r];
            }
        }
        __syncthreads();

        if (tid < 256) {
            float gi = bi, gf = bfr, gg = bgg, go = bo;
            #pragma unroll
            for (int w8 = 0; w8 < 8; ++w8) {
                const float* p = &pbuf[w8][rrow][0];
                gi += p[0 * 32 + rhc];
                gf += p[1 * 32 + rhc];
                gg += p[2 * 32 + rhc];
                go += p[3 * 32 + rhc];
            }
            const float i_ = 1.f / (1.f + __expf(-gi));
            const float f_ = 1.f / (1.f + __expf(-gf));
            const float g_ = tanhf(gg);
            const float o_ = 1.f / (1.f + __expf(-go));
            creg = f_ * creg + i_ * g_;
            const float h = o_ * tanhf(creg);
            if (t == TSTEPS - 1) {
                hf[(b0 + rrow) * HIDDEN + n0 + rhc] = h;
            } else {
                const u32 val = ((u32)(t + 1) << 16) | (u32)f2bu(h);
                __hip_atomic_store(ho + (b0 + rrow) * HIDDEN + n0 + rhc, val,
                                   __ATOMIC_RELAXED, __HIP_MEMORY_SCOPE_AGENT);
            }
        }
        if (t == TSTEPS - 1) break;
        __syncthreads();   // pbuf WAR for next step
    }
}

// ---------------------------------------------------------------------------
// Epilogue: out[64][256] = h_last(fp32) @ W_out + b_out
__global__ __launch_bounds__(256) void out_proj(
    const float* __restrict__ hf, const float* __restrict__ Wout,
    const float* __restrict__ bout, float* __restrict__ out)
{
    const int b  = blockIdx.x;    // 64
    const int oc = threadIdx.x;   // 256
    const float* hb = hf + (size_t)b * HIDDEN;
    float a0 = 0.f, a1 = 0.f, a2 = 0.f, a3 = 0.f;
    for (int k = 0; k < HIDDEN; k += 4) {
        a0 += hb[k + 0] * Wout[(size_t)(k + 0) * 256 + oc];
        a1 += hb[k + 1] * Wout[(size_t)(k + 1) * 256 + oc];
        a2 += hb[k + 2] * Wout[(size_t)(k + 2) * 256 + oc];
        a3 += hb[k + 3] * Wout[(size_t)(k + 3) * 256 + oc];
    }
    out[b * 256 + oc] = (a0 + a1) + (a2 + a3) + bout[oc];
}

// ---------------------------------------------------------------------------
extern "C" void kernel_launch(void* const* d_in, const int* in_sizes, int n_in,
                              void* d_out, int out_size, void* d_ws, size_t ws_size,
                              hipStream_t stream)
{
    const float* x    = (const float*)d_in[0];
    const float* Wih  = (const float*)d_in[1];
    const float* Whh  = (const float*)d_in[2];
    const float* bih  = (const float*)d_in[3];
    const float* bhh  = (const float*)d_in[4];
    const float* Wout = (const float*)d_in[5];
    const float* bout = (const float*)d_in[6];
    float* out = (float*)d_out;

    char* ws = (char*)d_ws;
    size_t off = 0;
    auto alloc = [&](size_t bytes) -> void* {
        void* p = ws + off;
        off = (off + bytes + 255) & ~(size_t)255;
        return p;
    };
    __hip_bfloat16* Wt = (__hip_bfloat16*)alloc((size_t)NGCOL * KTOT * 2); // 10 MB
    u32*   hbuf = (u32*)alloc((size_t)2 * HBUFN * 4);                      // 512 KB
    float* bias = (float*)alloc((size_t)NGCOL * 4);
    float* hf   = (float*)alloc((size_t)BATCH * HIDDEN * 4);

    build_wt<<<1280, 256, 0, stream>>>(Whh, Wih, Wt);
    init_state<<<512, 256, 0, stream>>>(bih, bhh, bias, hbuf);
    lstm_persist<<<256, 512, 0, stream>>>(Wt, x, hbuf, hf, bias);
    out_proj<<<64, 256, 0, stream>>>(hf, Wout, bout, out);
}